// Round 1
// baseline (232.855 us; speedup 1.0000x reference)
//
#include <hip/hip_runtime.h>
#include <hip/hip_bf16.h>

// Problem constants
#define B_   8
#define T_   8192
#define D_   128
#define K_   64
#define TC   16      // timesteps per chunk (one wave's serial run)

#define GEMM_BLOCKS 1024
#define GP 136       // LDS pitch (ushorts) for W hi/lo rows: 2-way bank aliasing only

typedef float  floatx4  __attribute__((ext_vector_type(4)));
typedef __bf16 bf16x8   __attribute__((ext_vector_type(8)));
typedef unsigned short ushortx8 __attribute__((ext_vector_type(8)));

__device__ inline unsigned short f2bf(float f) {
  unsigned u = __float_as_uint(f);
  u = u + 0x7FFFu + ((u >> 16) & 1u);   // RNE to bf16
  return (unsigned short)(u >> 16);
}
__device__ inline float bf2f(unsigned short h) {
  return __uint_as_float(((unsigned)h) << 16);
}

// ---------------------------------------------------------------------------
// K1+K2 fused: blocks 0..1023 do the GEMM V = x * W^T (unscaled, fp32-accurate
// via bf16 hi/lo split + MFMA); block 1024 computes 1/sigma into sig[0] and
// zeroes the cross-block flags used by the fused scan kernel.
// ---------------------------------------------------------------------------
#define MP 72  // sigma-path LDS pitch (ushorts)

__global__ __launch_bounds__(256) void k_gemm_sigma(
    const float* __restrict__ x, const float* __restrict__ W,
    float* __restrict__ V, float* __restrict__ sig, int* __restrict__ FL) {
  __shared__ __align__(16) unsigned char smem[2 * 64 * GP * 2 + 512];

  const int tid  = threadIdx.x;
  const int lane = tid & 63;
  const int wv   = tid >> 6;
  const int l15  = lane & 15;
  const int q    = lane >> 4;

  if (blockIdx.x == GEMM_BLOCKS) {
    // flags for k_fused (workspace is poisoned between replays; this kernel
    // strictly precedes k_fused on the stream, so zeroing here is safe)
    FL[tid] = 0;

    // ---------------- sigma path (one block) ----------------
    unsigned short* Ma = (unsigned short*)smem;            // 64*72
    unsigned short* Mb = Ma + 64 * MP;                     // 64*72
    float* red = (float*)(smem + 2 * 64 * MP * 2);
    float* vsh = red + 4;
    int*   jsh = (int*)(vsh + 64);

    // G = W W^T : tiles (tm=wv, tn=0..3), K=128 in 4 steps of 32
    floatx4 acc[4] = {};
    const int arow = 16 * wv + l15;
    for (int s = 0; s < 4; ++s) {
      const int kb = 32 * s + 8 * q;
      float4 a0 = *(const float4*)(W + arow * 128 + kb);
      float4 a1 = *(const float4*)(W + arow * 128 + kb + 4);
      ushortx8 ua;
      ua[0] = f2bf(a0.x); ua[1] = f2bf(a0.y); ua[2] = f2bf(a0.z); ua[3] = f2bf(a0.w);
      ua[4] = f2bf(a1.x); ua[5] = f2bf(a1.y); ua[6] = f2bf(a1.z); ua[7] = f2bf(a1.w);
      bf16x8 av = __builtin_bit_cast(bf16x8, ua);
      for (int tn = 0; tn < 4; ++tn) {
        const int brow = 16 * tn + l15;          // B[k][n] = W[n][k]
        float4 b0 = *(const float4*)(W + brow * 128 + kb);
        float4 b1 = *(const float4*)(W + brow * 128 + kb + 4);
        ushortx8 ub;
        ub[0] = f2bf(b0.x); ub[1] = f2bf(b0.y); ub[2] = f2bf(b0.z); ub[3] = f2bf(b0.w);
        ub[4] = f2bf(b1.x); ub[5] = f2bf(b1.y); ub[6] = f2bf(b1.z); ub[7] = f2bf(b1.w);
        bf16x8 bv = __builtin_bit_cast(bf16x8, ub);
        acc[tn] = __builtin_amdgcn_mfma_f32_16x16x32_bf16(av, bv, acc[tn], 0, 0, 0);
      }
    }
    float mx = 0.f;
    for (int tn = 0; tn < 4; ++tn)
      for (int r = 0; r < 4; ++r) mx = fmaxf(mx, fabsf(acc[tn][r]));
    for (int off = 32; off; off >>= 1) mx = fmaxf(mx, __shfl_xor(mx, off));
    if (lane == 0) red[wv] = mx;
    __syncthreads();
    {
      float gm  = fmaxf(fmaxf(red[0], red[1]), fmaxf(red[2], red[3]));
      float inv = 1.f / gm;
      for (int tn = 0; tn < 4; ++tn)
        for (int r = 0; r < 4; ++r)
          Ma[(16 * wv + 4 * q + r) * MP + 16 * tn + l15] = f2bf(acc[tn][r] * inv);
    }
    __syncthreads();

    unsigned short* src = Ma;
    unsigned short* dst = Mb;
    for (int it = 0; it < 8; ++it) {
      floatx4 f[4] = {};
      for (int s = 0; s < 2; ++s) {
        const int kb = 32 * s + 8 * q;
        uint4 ua4 = *(const uint4*)(src + (16 * wv + l15) * MP + kb);
        bf16x8 av = __builtin_bit_cast(bf16x8, ua4);
        for (int tn = 0; tn < 4; ++tn) {
          const int n = 16 * tn + l15;
          ushortx8 ub;
          #pragma unroll
          for (int j = 0; j < 8; ++j) ub[j] = src[(kb + j) * MP + n];
          bf16x8 bv = __builtin_bit_cast(bf16x8, ub);
          f[tn] = __builtin_amdgcn_mfma_f32_16x16x32_bf16(av, bv, f[tn], 0, 0, 0);
        }
      }
      float m2 = 0.f;
      for (int tn = 0; tn < 4; ++tn)
        for (int r = 0; r < 4; ++r) m2 = fmaxf(m2, fabsf(f[tn][r]));
      for (int off = 32; off; off >>= 1) m2 = fmaxf(m2, __shfl_xor(m2, off));
      if (lane == 0) red[wv] = m2;
      __syncthreads();
      {
        float gm2  = fmaxf(fmaxf(red[0], red[1]), fmaxf(red[2], red[3]));
        float inv2 = 1.f / gm2;
        for (int tn = 0; tn < 4; ++tn)
          for (int r = 0; r < 4; ++r)
            dst[(16 * wv + 4 * q + r) * MP + 16 * tn + l15] = f2bf(f[tn][r] * inv2);
      }
      __syncthreads();
      unsigned short* t2 = src; src = dst; dst = t2;
    }

    if (tid == 0) {
      int jb = 0; float best = -1.f;
      for (int j = 0; j < 64; ++j) {
        float dv = bf2f(src[j * MP + j]);
        if (dv > best) { best = dv; jb = j; }
      }
      *jsh = jb;
    }
    __syncthreads();
    if (tid < 64) vsh[tid] = bf2f(src[tid * MP + *jsh]);
    __syncthreads();

    if (wv == 0) {
      float wa = 0.f, wb = 0.f;
      for (int i = 0; i < 64; ++i) {
        float vi = vsh[i];
        wa = fmaf(W[i * 128 + lane], vi, wa);
        wb = fmaf(W[i * 128 + 64 + lane], vi, wb);
      }
      float num = wa * wa + wb * wb;
      float den = vsh[lane] * vsh[lane];
      for (int off = 32; off; off >>= 1) {
        num += __shfl_xor(num, off);
        den += __shfl_xor(den, off);
      }
      if (lane == 0) sig[0] = 1.f / sqrtf(num / den);
    }
    return;
  }

  // ---------------- GEMM path ----------------
  unsigned short* Wh = (unsigned short*)smem;   // [64][GP]
  unsigned short* Wl = Wh + 64 * GP;

  // stage W -> bf16 hi/lo in LDS (coalesced float4 loads)
  #pragma unroll
  for (int j = 0; j < 8; ++j) {
    const int v = tid + 256 * j;           // float4 index, 0..2047
    float4 w4 = ((const float4*)W)[v];
    const int e = v * 4;
    const int row = e >> 7, col = e & 127;
    float a[4] = {w4.x, w4.y, w4.z, w4.w};
    unsigned short h[4], l[4];
    #pragma unroll
    for (int i = 0; i < 4; ++i) {
      h[i] = f2bf(a[i]);
      l[i] = f2bf(a[i] - bf2f(h[i]));
    }
    unsigned hp0 = (unsigned)h[0] | ((unsigned)h[1] << 16);
    unsigned hp1 = (unsigned)h[2] | ((unsigned)h[3] << 16);
    unsigned lp0 = (unsigned)l[0] | ((unsigned)l[1] << 16);
    unsigned lp1 = (unsigned)l[2] | ((unsigned)l[3] << 16);
    *(uint2*)(Wh + row * GP + col) = make_uint2(hp0, hp1);
    *(uint2*)(Wl + row * GP + col) = make_uint2(lp0, lp1);
  }
  __syncthreads();

  const int R0 = blockIdx.x * 64 + wv * 16;   // 16 rows per wave
  floatx4 acc[4] = {};

  #pragma unroll
  for (int s = 0; s < 4; ++s) {
    const float* xp = x + ((size_t)(R0 + l15) << 7) + 32 * s + 8 * q;
    float4 x0 = *(const float4*)xp;
    float4 x1 = *(const float4*)(xp + 4);
    float xs8[8] = {x0.x, x0.y, x0.z, x0.w, x1.x, x1.y, x1.z, x1.w};
    ushortx8 uh, ul;
    #pragma unroll
    for (int j = 0; j < 8; ++j) {
      unsigned short h = f2bf(xs8[j]);
      uh[j] = h;
      ul[j] = f2bf(xs8[j] - bf2f(h));
    }
    bf16x8 ah = __builtin_bit_cast(bf16x8, uh);
    bf16x8 al = __builtin_bit_cast(bf16x8, ul);

    #pragma unroll
    for (int t = 0; t < 4; ++t) {
      const unsigned short* bp = Wh + (16 * t + l15) * GP + 32 * s + 8 * q;
      bf16x8 bh = __builtin_bit_cast(bf16x8, *(const uint4*)bp);
      const unsigned short* bq = Wl + (16 * t + l15) * GP + 32 * s + 8 * q;
      bf16x8 bl = __builtin_bit_cast(bf16x8, *(const uint4*)bq);
      acc[t] = __builtin_amdgcn_mfma_f32_16x16x32_bf16(ah, bh, acc[t], 0, 0, 0);
      acc[t] = __builtin_amdgcn_mfma_f32_16x16x32_bf16(al, bh, acc[t], 0, 0, 0);
      acc[t] = __builtin_amdgcn_mfma_f32_16x16x32_bf16(ah, bl, acc[t], 0, 0, 0);
    }
  }

  // store: C layout col = l15, row = 4q + r
  #pragma unroll
  for (int t = 0; t < 4; ++t)
    #pragma unroll
    for (int r = 0; r < 4; ++r)
      V[(size_t)(R0 + 4 * q + r) * 64 + 16 * t + l15] = acc[t][r];
}

// Shared per-step math (|theta| < 1.6e-3 so 2-term poly is exact)
#define STEP_PREP()                                                     \
    float alpha = alpha0 * __expf(a_ + tmv);                            \
    float omega = omega0 * __expf(o_ + tmv);                            \
    float rho = __expf(-alpha * dtv);                                   \
    float th  = omega * dtv;                                            \
    float th2 = th * th;                                                \
    float st  = th * fmaf(th2, -0.16666667f, 1.f);                      \
    float ct  = fmaf(th2, -0.5f, 1.f);                                  \
    float ar  = rho * ct, ai = rho * st;

// ---------------------------------------------------------------------------
// Fused scan: replaces phaseA + segagg + segscan + phaseC.
// Grid 256 blocks x 1024 threads. Block g: b = g>>5, time stripe tb = g&31
// (256 timesteps). Wave w (16 waves) owns one 16-step chunk, lane = k.
// Phase 1: compute (ar,ai,u) per step, CACHE IN REGISTERS, and build the
//          chunk transform; block aggregate published to BA[g] + release flag.
// Phase 2: spin (acquire, agent scope) on the <=31 same-b predecessor flags,
//          compose their aggregates -> incoming state.
// Phase 3: replay 16 steps from the register cache, write out.
// Single read of am/om/V; single transcendental pass; out written once.
// ---------------------------------------------------------------------------
__global__ __launch_bounds__(1024, 8) void k_fused(
    const float* __restrict__ am, const float* __restrict__ om,
    const float* __restrict__ tm, const float* __restrict__ dtp,
    const float* __restrict__ V,  const float* __restrict__ sr,
    const float* __restrict__ si, const float* __restrict__ traw,
    const float* __restrict__ bb, const float* __restrict__ sig,
    float* __restrict__ BA, int* __restrict__ FL,
    float* __restrict__ out) {
  __shared__ float4 sAgg[16 * 64];   // per-chunk transforms (A,U), 16 KB

  const int tid  = threadIdx.x;
  const int lane = tid & 63;
  const int w    = __builtin_amdgcn_readfirstlane(tid >> 6);  // chunk 0..15
  const int g    = blockIdx.x;       // 0..255
  const int b    = g >> 5;
  const int tb   = g & 31;
  const int gb   = g & ~31;

  const float tau    = log1pf(__expf(traw[0])) + 1e-3f;
  const float alpha0 = (log1pf(__expf(sr[lane])) + 1e-6f) * tau;
  const float omega0 = si[lane] * tau;
  const float bk     = bb[lane];
  const float invs   = sig[0];

  const int bt0 = b * T_ + tb * 256 + w * TC;
  size_t base = (size_t)bt0 * 64 + lane;

  // ---- Phase 1: per-step coefficients (cached) + chunk transform ----
  float car[TC], cai[TC], cu[TC];
  float Ar = 1.f, Ai = 0.f, Ur = 0.f, Ui = 0.f;
  #pragma unroll
  for (int t = 0; t < TC; ++t) {
    float a_  = am[base];
    float o_  = om[base];
    float v_  = V[base];
    float tmv = tm[bt0 + t];
    float dtv = dtp[bt0 + t];
    STEP_PREP();
    float u = fmaf(v_, invs, bk);
    car[t] = ar; cai[t] = ai; cu[t] = u;
    float nUr = fmaf(ar, Ur, fmaf(-ai, Ui, u));
    float nUi = fmaf(ar, Ui, ai * Ur);
    Ur = nUr; Ui = nUi;
    float nAr = fmaf(ar, Ar, -ai * Ai);
    float nAi = fmaf(ar, Ai, ai * Ar);
    Ar = nAr; Ai = nAi;
    base += 64;
  }
  sAgg[w * 64 + lane] = make_float4(Ar, Ai, Ur, Ui);
  __syncthreads();

  // ---- exclusive within-block prefix E over chunks 0..w-1 ----
  float Er = 1.f, Ei = 0.f, Fr = 0.f, Fi = 0.f;
  for (int j = 0; j < w; ++j) {
    float4 a = sAgg[j * 64 + lane];
    float nEr = a.x * Er - a.y * Ei;
    float nEi = a.x * Ei + a.y * Er;
    float nFr = fmaf(a.x, Fr, fmaf(-a.y, Fi, a.z));
    float nFi = fmaf(a.x, Fi, fmaf(a.y, Fr, a.w));
    Er = nEr; Ei = nEi; Fr = nFr; Fi = nFi;
  }

  // ---- wave 15 publishes the block aggregate = chunk15 ∘ E15 ----
  if (w == 15) {
    float bAr = Ar * Er - Ai * Ei;
    float bAi = Ar * Ei + Ai * Er;
    float bUr = fmaf(Ar, Fr, fmaf(-Ai, Fi, Ur));
    float bUi = fmaf(Ar, Fi, fmaf(Ai, Fr, Ui));
    *(float4*)(BA + (size_t)(g * 64 + lane) * 4) = make_float4(bAr, bAi, bUr, bUi);
    __threadfence();            // agent-scope writeback before flag release
  }
  __syncthreads();
  if (tid == 0)
    __hip_atomic_store(&FL[g], 1, __ATOMIC_RELEASE, __HIP_MEMORY_SCOPE_AGENT);

  // ---- Phase 2: wait for same-b predecessors, compose incoming state ----
  if (tid < tb) {
    while (__hip_atomic_load(&FL[gb + tid], __ATOMIC_ACQUIRE,
                             __HIP_MEMORY_SCOPE_AGENT) == 0)
      __builtin_amdgcn_s_sleep(2);
  }
  __syncthreads();
  __threadfence();              // acquire-side invalidate for all readers

  float Hr = 0.f, Hi = 0.f;     // state entering this block = U of composed prefix
  for (int j = 0; j < tb; ++j) {
    float4 a = *(const float4*)(BA + (size_t)((gb + j) * 64 + lane) * 4);
    float nHr = fmaf(a.x, Hr, fmaf(-a.y, Hi, a.z));
    float nHi = fmaf(a.x, Hi, fmaf(a.y, Hr, a.w));
    Hr = nHr; Hi = nHi;
  }
  // state entering this wave's chunk: z0 = E.A * H + E.U
  float zr = fmaf(Er, Hr, fmaf(-Ei, Hi, Fr));
  float zi = fmaf(Er, Hi, fmaf(Ei, Hr, Fi));

  // ---- Phase 3: replay from register cache, write output ----
  float* outp = out + (size_t)bt0 * 128 + lane;
  #pragma unroll
  for (int t = 0; t < TC; ++t) {
    float nr = fmaf(car[t], zr, fmaf(-cai[t], zi, cu[t]));
    float ni = fmaf(car[t], zi, cai[t] * zr);
    zr = nr; zi = ni;
    outp[0]  = zr;     // C
    outp[64] = zi;     // S
    outp += 128;
  }
}

// ---------------------------------------------------------------------------
extern "C" void kernel_launch(void* const* d_in, const int* in_sizes, int n_in,
                              void* d_out, int out_size, void* d_ws, size_t ws_size,
                              hipStream_t stream) {
  (void)in_sizes; (void)n_in; (void)out_size; (void)ws_size;
  const float* x    = (const float*)d_in[0];
  const float* dtp  = (const float*)d_in[1];
  const float* amod = (const float*)d_in[2];
  const float* omod = (const float*)d_in[3];
  const float* tmod = (const float*)d_in[4];
  const float* srr  = (const float*)d_in[5];
  const float* sim  = (const float*)d_in[6];
  const float* traw = (const float*)d_in[7];
  const float* W    = (const float*)d_in[8];
  const float* bb   = (const float*)d_in[9];
  float* out = (float*)d_out;
  float* ws  = (float*)d_ws;

  float* sig = ws;                                   // [16]
  float* V   = ws + 16;                              // B*T*K = 4,194,304
  float* BA  = V + (size_t)B_ * T_ * K_;             // 256*64*4 = 65,536
  int*   FL  = (int*)(BA + 256 * 64 * 4);            // [256]

  k_gemm_sigma<<<GEMM_BLOCKS + 1, 256, 0, stream>>>(x, W, V, sig, FL);
  k_fused<<<256, 1024, 0, stream>>>(amod, omod, tmod, dtp, V, srr, sim, traw,
                                    bb, sig, BA, FL, out);
}

// Round 2
// 220.358 us; speedup vs baseline: 1.0567x; 1.0567x over previous
//
#include <hip/hip_runtime.h>
#include <hip/hip_bf16.h>

// Problem constants
#define B_   8
#define T_   8192
#define D_   128
#define K_   64
#define TC   16      // timesteps per chunk (one wave's serial run)

#define GEMM_BLOCKS 1024
#define GP 136       // LDS pitch (ushorts) for W hi/lo rows: 2-way bank aliasing only

typedef float  floatx4  __attribute__((ext_vector_type(4)));
typedef __bf16 bf16x8   __attribute__((ext_vector_type(8)));
typedef unsigned short ushortx8 __attribute__((ext_vector_type(8)));

__device__ inline unsigned short f2bf(float f) {
  unsigned u = __float_as_uint(f);
  u = u + 0x7FFFu + ((u >> 16) & 1u);   // RNE to bf16
  return (unsigned short)(u >> 16);
}
__device__ inline float bf2f(unsigned short h) {
  return __uint_as_float(((unsigned)h) << 16);
}

// ---------------------------------------------------------------------------
// K1+K2 fused: blocks 0..1023 do the GEMM V = x * W^T (unscaled, fp32-accurate
// via bf16 hi/lo split + MFMA); block 1024 computes 1/sigma into sig[0] and
// zeroes the cross-block flags used by the fused scan kernel.
// ---------------------------------------------------------------------------
#define MP 72  // sigma-path LDS pitch (ushorts)

__global__ __launch_bounds__(256) void k_gemm_sigma(
    const float* __restrict__ x, const float* __restrict__ W,
    float* __restrict__ V, float* __restrict__ sig, int* __restrict__ FL) {
  __shared__ __align__(16) unsigned char smem[2 * 64 * GP * 2 + 512];

  const int tid  = threadIdx.x;
  const int lane = tid & 63;
  const int wv   = tid >> 6;
  const int l15  = lane & 15;
  const int q    = lane >> 4;

  if (blockIdx.x == GEMM_BLOCKS) {
    // flags for k_fused (workspace is poisoned between replays; this kernel
    // strictly precedes k_fused on the stream, so zeroing here is safe)
    FL[tid] = 0;

    // ---------------- sigma path (one block) ----------------
    unsigned short* Ma = (unsigned short*)smem;            // 64*72
    unsigned short* Mb = Ma + 64 * MP;                     // 64*72
    float* red = (float*)(smem + 2 * 64 * MP * 2);
    float* vsh = red + 4;
    int*   jsh = (int*)(vsh + 64);

    // G = W W^T : tiles (tm=wv, tn=0..3), K=128 in 4 steps of 32
    floatx4 acc[4] = {};
    const int arow = 16 * wv + l15;
    for (int s = 0; s < 4; ++s) {
      const int kb = 32 * s + 8 * q;
      float4 a0 = *(const float4*)(W + arow * 128 + kb);
      float4 a1 = *(const float4*)(W + arow * 128 + kb + 4);
      ushortx8 ua;
      ua[0] = f2bf(a0.x); ua[1] = f2bf(a0.y); ua[2] = f2bf(a0.z); ua[3] = f2bf(a0.w);
      ua[4] = f2bf(a1.x); ua[5] = f2bf(a1.y); ua[6] = f2bf(a1.z); ua[7] = f2bf(a1.w);
      bf16x8 av = __builtin_bit_cast(bf16x8, ua);
      for (int tn = 0; tn < 4; ++tn) {
        const int brow = 16 * tn + l15;          // B[k][n] = W[n][k]
        float4 b0 = *(const float4*)(W + brow * 128 + kb);
        float4 b1 = *(const float4*)(W + brow * 128 + kb + 4);
        ushortx8 ub;
        ub[0] = f2bf(b0.x); ub[1] = f2bf(b0.y); ub[2] = f2bf(b0.z); ub[3] = f2bf(b0.w);
        ub[4] = f2bf(b1.x); ub[5] = f2bf(b1.y); ub[6] = f2bf(b1.z); ub[7] = f2bf(b1.w);
        bf16x8 bv = __builtin_bit_cast(bf16x8, ub);
        acc[tn] = __builtin_amdgcn_mfma_f32_16x16x32_bf16(av, bv, acc[tn], 0, 0, 0);
      }
    }
    float mx = 0.f;
    for (int tn = 0; tn < 4; ++tn)
      for (int r = 0; r < 4; ++r) mx = fmaxf(mx, fabsf(acc[tn][r]));
    for (int off = 32; off; off >>= 1) mx = fmaxf(mx, __shfl_xor(mx, off));
    if (lane == 0) red[wv] = mx;
    __syncthreads();
    {
      float gm  = fmaxf(fmaxf(red[0], red[1]), fmaxf(red[2], red[3]));
      float inv = 1.f / gm;
      for (int tn = 0; tn < 4; ++tn)
        for (int r = 0; r < 4; ++r)
          Ma[(16 * wv + 4 * q + r) * MP + 16 * tn + l15] = f2bf(acc[tn][r] * inv);
    }
    __syncthreads();

    unsigned short* src = Ma;
    unsigned short* dst = Mb;
    for (int it = 0; it < 8; ++it) {
      floatx4 f[4] = {};
      for (int s = 0; s < 2; ++s) {
        const int kb = 32 * s + 8 * q;
        uint4 ua4 = *(const uint4*)(src + (16 * wv + l15) * MP + kb);
        bf16x8 av = __builtin_bit_cast(bf16x8, ua4);
        for (int tn = 0; tn < 4; ++tn) {
          const int n = 16 * tn + l15;
          ushortx8 ub;
          #pragma unroll
          for (int j = 0; j < 8; ++j) ub[j] = src[(kb + j) * MP + n];
          bf16x8 bv = __builtin_bit_cast(bf16x8, ub);
          f[tn] = __builtin_amdgcn_mfma_f32_16x16x32_bf16(av, bv, f[tn], 0, 0, 0);
        }
      }
      float m2 = 0.f;
      for (int tn = 0; tn < 4; ++tn)
        for (int r = 0; r < 4; ++r) m2 = fmaxf(m2, fabsf(f[tn][r]));
      for (int off = 32; off; off >>= 1) m2 = fmaxf(m2, __shfl_xor(m2, off));
      if (lane == 0) red[wv] = m2;
      __syncthreads();
      {
        float gm2  = fmaxf(fmaxf(red[0], red[1]), fmaxf(red[2], red[3]));
        float inv2 = 1.f / gm2;
        for (int tn = 0; tn < 4; ++tn)
          for (int r = 0; r < 4; ++r)
            dst[(16 * wv + 4 * q + r) * MP + 16 * tn + l15] = f2bf(f[tn][r] * inv2);
      }
      __syncthreads();
      unsigned short* t2 = src; src = dst; dst = t2;
    }

    if (tid == 0) {
      int jb = 0; float best = -1.f;
      for (int j = 0; j < 64; ++j) {
        float dv = bf2f(src[j * MP + j]);
        if (dv > best) { best = dv; jb = j; }
      }
      *jsh = jb;
    }
    __syncthreads();
    if (tid < 64) vsh[tid] = bf2f(src[tid * MP + *jsh]);
    __syncthreads();

    if (wv == 0) {
      float wa = 0.f, wb = 0.f;
      for (int i = 0; i < 64; ++i) {
        float vi = vsh[i];
        wa = fmaf(W[i * 128 + lane], vi, wa);
        wb = fmaf(W[i * 128 + 64 + lane], vi, wb);
      }
      float num = wa * wa + wb * wb;
      float den = vsh[lane] * vsh[lane];
      for (int off = 32; off; off >>= 1) {
        num += __shfl_xor(num, off);
        den += __shfl_xor(den, off);
      }
      if (lane == 0) sig[0] = 1.f / sqrtf(num / den);
    }
    return;
  }

  // ---------------- GEMM path ----------------
  unsigned short* Wh = (unsigned short*)smem;   // [64][GP]
  unsigned short* Wl = Wh + 64 * GP;

  // stage W -> bf16 hi/lo in LDS (coalesced float4 loads)
  #pragma unroll
  for (int j = 0; j < 8; ++j) {
    const int v = tid + 256 * j;           // float4 index, 0..2047
    float4 w4 = ((const float4*)W)[v];
    const int e = v * 4;
    const int row = e >> 7, col = e & 127;
    float a[4] = {w4.x, w4.y, w4.z, w4.w};
    unsigned short h[4], l[4];
    #pragma unroll
    for (int i = 0; i < 4; ++i) {
      h[i] = f2bf(a[i]);
      l[i] = f2bf(a[i] - bf2f(h[i]));
    }
    unsigned hp0 = (unsigned)h[0] | ((unsigned)h[1] << 16);
    unsigned hp1 = (unsigned)h[2] | ((unsigned)h[3] << 16);
    unsigned lp0 = (unsigned)l[0] | ((unsigned)l[1] << 16);
    unsigned lp1 = (unsigned)l[2] | ((unsigned)l[3] << 16);
    *(uint2*)(Wh + row * GP + col) = make_uint2(hp0, hp1);
    *(uint2*)(Wl + row * GP + col) = make_uint2(lp0, lp1);
  }
  __syncthreads();

  const int R0 = blockIdx.x * 64 + wv * 16;   // 16 rows per wave
  floatx4 acc[4] = {};

  #pragma unroll
  for (int s = 0; s < 4; ++s) {
    const float* xp = x + ((size_t)(R0 + l15) << 7) + 32 * s + 8 * q;
    float4 x0 = *(const float4*)xp;
    float4 x1 = *(const float4*)(xp + 4);
    float xs8[8] = {x0.x, x0.y, x0.z, x0.w, x1.x, x1.y, x1.z, x1.w};
    ushortx8 uh, ul;
    #pragma unroll
    for (int j = 0; j < 8; ++j) {
      unsigned short h = f2bf(xs8[j]);
      uh[j] = h;
      ul[j] = f2bf(xs8[j] - bf2f(h));
    }
    bf16x8 ah = __builtin_bit_cast(bf16x8, uh);
    bf16x8 al = __builtin_bit_cast(bf16x8, ul);

    #pragma unroll
    for (int t = 0; t < 4; ++t) {
      const unsigned short* bp = Wh + (16 * t + l15) * GP + 32 * s + 8 * q;
      bf16x8 bh = __builtin_bit_cast(bf16x8, *(const uint4*)bp);
      const unsigned short* bq = Wl + (16 * t + l15) * GP + 32 * s + 8 * q;
      bf16x8 bl = __builtin_bit_cast(bf16x8, *(const uint4*)bq);
      acc[t] = __builtin_amdgcn_mfma_f32_16x16x32_bf16(ah, bh, acc[t], 0, 0, 0);
      acc[t] = __builtin_amdgcn_mfma_f32_16x16x32_bf16(al, bh, acc[t], 0, 0, 0);
      acc[t] = __builtin_amdgcn_mfma_f32_16x16x32_bf16(ah, bl, acc[t], 0, 0, 0);
    }
  }

  // store: C layout col = l15, row = 4q + r
  #pragma unroll
  for (int t = 0; t < 4; ++t)
    #pragma unroll
    for (int r = 0; r < 4; ++r)
      V[(size_t)(R0 + 4 * q + r) * 64 + 16 * t + l15] = acc[t][r];
}

// Shared per-step math (|theta| < 1.6e-3 so 2-term poly is exact)
#define STEP_PREP()                                                     \
    float alpha = alpha0 * __expf(a_ + tmv);                            \
    float omega = omega0 * __expf(o_ + tmv);                            \
    float rho = __expf(-alpha * dtv);                                   \
    float th  = omega * dtv;                                            \
    float th2 = th * th;                                                \
    float st  = th * fmaf(th2, -0.16666667f, 1.f);                      \
    float ct  = fmaf(th2, -0.5f, 1.f);                                  \
    float ar  = rho * ct, ai = rho * st;

// ---------------------------------------------------------------------------
// Fused scan: replaces phaseA + segagg + segscan + phaseC.
// Grid 256 blocks x 1024 threads. Block g: b = g>>5, time stripe tb = g&31
// (256 timesteps). Wave w (16 waves) owns one 16-step chunk, lane = k.
//
// __launch_bounds__(1024, 4): a 1024-thread block is 16 waves = 4 waves/SIMD,
// so 4 is the natural (and maximum-VGPR, 128/wave) residency demand. R1's
// (1024, 8) capped VGPRs at 64 and spilled the 48-float register cache to
// scratch -> 110 us latency-bound. Grid 256 = #CUs keeps every block
// co-resident (deadlock-free flag spin).
// ---------------------------------------------------------------------------
__global__ __launch_bounds__(1024, 4) void k_fused(
    const float* __restrict__ am, const float* __restrict__ om,
    const float* __restrict__ tm, const float* __restrict__ dtp,
    const float* __restrict__ V,  const float* __restrict__ sr,
    const float* __restrict__ si, const float* __restrict__ traw,
    const float* __restrict__ bb, const float* __restrict__ sig,
    float* __restrict__ BA, int* __restrict__ FL,
    float* __restrict__ out) {
  __shared__ float4 sAgg[16 * 64];   // per-chunk transforms (A,U), 16 KB

  const int tid  = threadIdx.x;
  const int lane = tid & 63;
  const int w    = __builtin_amdgcn_readfirstlane(tid >> 6);  // chunk 0..15
  const int g    = blockIdx.x;       // 0..255
  const int b    = g >> 5;
  const int tb   = g & 31;
  const int gb   = g & ~31;

  const float tau    = log1pf(__expf(traw[0])) + 1e-3f;
  const float alpha0 = (log1pf(__expf(sr[lane])) + 1e-6f) * tau;
  const float omega0 = si[lane] * tau;
  const float bk     = bb[lane];
  const float invs   = sig[0];

  const int bt0 = b * T_ + tb * 256 + w * TC;
  size_t base = (size_t)bt0 * 64 + lane;

  // ---- Phase 1: per-step coefficients (cached in VGPRs) + chunk transform ----
  float car[TC], cai[TC], cu[TC];
  float Ar = 1.f, Ai = 0.f, Ur = 0.f, Ui = 0.f;
  #pragma unroll
  for (int t = 0; t < TC; ++t) {
    float a_  = am[base];
    float o_  = om[base];
    float v_  = V[base];
    float tmv = tm[bt0 + t];
    float dtv = dtp[bt0 + t];
    STEP_PREP();
    float u = fmaf(v_, invs, bk);
    car[t] = ar; cai[t] = ai; cu[t] = u;
    float nUr = fmaf(ar, Ur, fmaf(-ai, Ui, u));
    float nUi = fmaf(ar, Ui, ai * Ur);
    Ur = nUr; Ui = nUi;
    float nAr = fmaf(ar, Ar, -ai * Ai);
    float nAi = fmaf(ar, Ai, ai * Ar);
    Ar = nAr; Ai = nAi;
    base += 64;
  }
  sAgg[w * 64 + lane] = make_float4(Ar, Ai, Ur, Ui);
  __syncthreads();

  // ---- exclusive within-block prefix E over chunks 0..w-1 ----
  // Always-load all 15 predecessors (independent LDS reads pipeline);
  // compose predicated with the identity so the chain stays branch-free.
  float Er = 1.f, Ei = 0.f, Fr = 0.f, Fi = 0.f;
  #pragma unroll
  for (int j = 0; j < 15; ++j) {
    float4 a = sAgg[j * 64 + lane];
    bool p = (j < w);
    float ax = p ? a.x : 1.f;
    float ay = p ? a.y : 0.f;
    float az = p ? a.z : 0.f;
    float aw_ = p ? a.w : 0.f;
    float nEr = ax * Er - ay * Ei;
    float nEi = ax * Ei + ay * Er;
    float nFr = fmaf(ax, Fr, fmaf(-ay, Fi, az));
    float nFi = fmaf(ax, Fi, fmaf(ay, Fr, aw_));
    Er = nEr; Ei = nEi; Fr = nFr; Fi = nFi;
  }

  // ---- wave 15 publishes the block aggregate = chunk15 ∘ E15 ----
  if (w == 15) {
    float bAr = Ar * Er - Ai * Ei;
    float bAi = Ar * Ei + Ai * Er;
    float bUr = fmaf(Ar, Fr, fmaf(-Ai, Fi, Ur));
    float bUi = fmaf(Ar, Fi, fmaf(Ai, Fr, Ui));
    *(float4*)(BA + (size_t)(g * 64 + lane) * 4) = make_float4(bAr, bAi, bUr, bUi);
    __threadfence();            // agent-scope writeback before flag release
  }
  __syncthreads();
  if (tid == 0)
    __hip_atomic_store(&FL[g], 1, __ATOMIC_RELEASE, __HIP_MEMORY_SCOPE_AGENT);

  // ---- Phase 2: wait for same-b predecessors, compose incoming state ----
  if (tid < tb) {
    while (__hip_atomic_load(&FL[gb + tid], __ATOMIC_ACQUIRE,
                             __HIP_MEMORY_SCOPE_AGENT) == 0)
      __builtin_amdgcn_s_sleep(2);
  }
  __syncthreads();
  __threadfence();              // acquire-side invalidate for all readers

  // Compose predecessors in batches of 8: loads within a batch are
  // independent (one latency exposure per batch, max 4) instead of 31
  // serial dependent loads. OOB lanes compose with the identity.
  float Hr = 0.f, Hi = 0.f;
  for (int j0 = 0; j0 < tb; j0 += 8) {
    float4 a[8];
    #pragma unroll
    for (int j = 0; j < 8; ++j) {
      if (j0 + j < tb)
        a[j] = *(const float4*)(BA + (size_t)((gb + j0 + j) * 64 + lane) * 4);
      else
        a[j] = make_float4(1.f, 0.f, 0.f, 0.f);
    }
    #pragma unroll
    for (int j = 0; j < 8; ++j) {
      float nHr = fmaf(a[j].x, Hr, fmaf(-a[j].y, Hi, a[j].z));
      float nHi = fmaf(a[j].x, Hi, fmaf(a[j].y, Hr, a[j].w));
      Hr = nHr; Hi = nHi;
    }
  }
  // state entering this wave's chunk: z0 = E.A * H + E.U
  float zr = fmaf(Er, Hr, fmaf(-Ei, Hi, Fr));
  float zi = fmaf(Er, Hi, fmaf(Ei, Hr, Fi));

  // ---- Phase 3: replay from register cache, write output ----
  float* outp = out + (size_t)bt0 * 128 + lane;
  #pragma unroll
  for (int t = 0; t < TC; ++t) {
    float nr = fmaf(car[t], zr, fmaf(-cai[t], zi, cu[t]));
    float ni = fmaf(car[t], zi, cai[t] * zr);
    zr = nr; zi = ni;
    outp[0]  = zr;     // C
    outp[64] = zi;     // S
    outp += 128;
  }
}

// ---------------------------------------------------------------------------
extern "C" void kernel_launch(void* const* d_in, const int* in_sizes, int n_in,
                              void* d_out, int out_size, void* d_ws, size_t ws_size,
                              hipStream_t stream) {
  (void)in_sizes; (void)n_in; (void)out_size; (void)ws_size;
  const float* x    = (const float*)d_in[0];
  const float* dtp  = (const float*)d_in[1];
  const float* amod = (const float*)d_in[2];
  const float* omod = (const float*)d_in[3];
  const float* tmod = (const float*)d_in[4];
  const float* srr  = (const float*)d_in[5];
  const float* sim  = (const float*)d_in[6];
  const float* traw = (const float*)d_in[7];
  const float* W    = (const float*)d_in[8];
  const float* bb   = (const float*)d_in[9];
  float* out = (float*)d_out;
  float* ws  = (float*)d_ws;

  float* sig = ws;                                   // [16]
  float* V   = ws + 16;                              // B*T*K = 4,194,304
  float* BA  = V + (size_t)B_ * T_ * K_;             // 256*64*4 = 65,536
  int*   FL  = (int*)(BA + 256 * 64 * 4);            // [256]

  k_gemm_sigma<<<GEMM_BLOCKS + 1, 256, 0, stream>>>(x, W, V, sig, FL);
  k_fused<<<256, 1024, 0, stream>>>(amod, omod, tmod, dtp, V, srr, sim, traw,
                                    bb, sig, BA, FL, out);
}

// Round 3
// 219.084 us; speedup vs baseline: 1.0629x; 1.0058x over previous
//
#include <hip/hip_runtime.h>
#include <hip/hip_bf16.h>

// Problem constants
#define B_   8
#define T_   8192
#define D_   128
#define K_   64
#define TC   16      // timesteps per chunk (one wave's serial run)

#define GEMM_BLOCKS 1024
#define GP 136       // LDS pitch (ushorts) for W hi/lo rows: 2-way bank aliasing only

typedef float  floatx4  __attribute__((ext_vector_type(4)));
typedef __bf16 bf16x8   __attribute__((ext_vector_type(8)));
typedef unsigned short ushortx8 __attribute__((ext_vector_type(8)));

__device__ inline unsigned short f2bf(float f) {
  unsigned u = __float_as_uint(f);
  u = u + 0x7FFFu + ((u >> 16) & 1u);   // RNE to bf16
  return (unsigned short)(u >> 16);
}
__device__ inline float bf2f(unsigned short h) {
  return __uint_as_float(((unsigned)h) << 16);
}

// ---------------------------------------------------------------------------
// K1+K2 fused: blocks 0..1023 do the GEMM V = x * W^T (unscaled, fp32-accurate
// via bf16 hi/lo split + MFMA); block 1024 computes 1/sigma into sig[0] and
// zeroes the cross-block flags used by the fused scan kernel.
// ---------------------------------------------------------------------------
#define MP 72  // sigma-path LDS pitch (ushorts)

__global__ __launch_bounds__(256) void k_gemm_sigma(
    const float* __restrict__ x, const float* __restrict__ W,
    float* __restrict__ V, float* __restrict__ sig, int* __restrict__ FL) {
  __shared__ __align__(16) unsigned char smem[2 * 64 * GP * 2 + 512];

  const int tid  = threadIdx.x;
  const int lane = tid & 63;
  const int wv   = tid >> 6;
  const int l15  = lane & 15;
  const int q    = lane >> 4;

  if (blockIdx.x == GEMM_BLOCKS) {
    // flags for k_fused (workspace is poisoned between replays; this kernel
    // strictly precedes k_fused on the stream, so zeroing here is safe)
    FL[tid] = 0;

    // ---------------- sigma path (one block) ----------------
    unsigned short* Ma = (unsigned short*)smem;            // 64*72
    unsigned short* Mb = Ma + 64 * MP;                     // 64*72
    float* red = (float*)(smem + 2 * 64 * MP * 2);
    float* vsh = red + 4;
    int*   jsh = (int*)(vsh + 64);

    // G = W W^T : tiles (tm=wv, tn=0..3), K=128 in 4 steps of 32
    floatx4 acc[4] = {};
    const int arow = 16 * wv + l15;
    for (int s = 0; s < 4; ++s) {
      const int kb = 32 * s + 8 * q;
      float4 a0 = *(const float4*)(W + arow * 128 + kb);
      float4 a1 = *(const float4*)(W + arow * 128 + kb + 4);
      ushortx8 ua;
      ua[0] = f2bf(a0.x); ua[1] = f2bf(a0.y); ua[2] = f2bf(a0.z); ua[3] = f2bf(a0.w);
      ua[4] = f2bf(a1.x); ua[5] = f2bf(a1.y); ua[6] = f2bf(a1.z); ua[7] = f2bf(a1.w);
      bf16x8 av = __builtin_bit_cast(bf16x8, ua);
      for (int tn = 0; tn < 4; ++tn) {
        const int brow = 16 * tn + l15;          // B[k][n] = W[n][k]
        float4 b0 = *(const float4*)(W + brow * 128 + kb);
        float4 b1 = *(const float4*)(W + brow * 128 + kb + 4);
        ushortx8 ub;
        ub[0] = f2bf(b0.x); ub[1] = f2bf(b0.y); ub[2] = f2bf(b0.z); ub[3] = f2bf(b0.w);
        ub[4] = f2bf(b1.x); ub[5] = f2bf(b1.y); ub[6] = f2bf(b1.z); ub[7] = f2bf(b1.w);
        bf16x8 bv = __builtin_bit_cast(bf16x8, ub);
        acc[tn] = __builtin_amdgcn_mfma_f32_16x16x32_bf16(av, bv, acc[tn], 0, 0, 0);
      }
    }
    float mx = 0.f;
    for (int tn = 0; tn < 4; ++tn)
      for (int r = 0; r < 4; ++r) mx = fmaxf(mx, fabsf(acc[tn][r]));
    for (int off = 32; off; off >>= 1) mx = fmaxf(mx, __shfl_xor(mx, off));
    if (lane == 0) red[wv] = mx;
    __syncthreads();
    {
      float gm  = fmaxf(fmaxf(red[0], red[1]), fmaxf(red[2], red[3]));
      float inv = 1.f / gm;
      for (int tn = 0; tn < 4; ++tn)
        for (int r = 0; r < 4; ++r)
          Ma[(16 * wv + 4 * q + r) * MP + 16 * tn + l15] = f2bf(acc[tn][r] * inv);
    }
    __syncthreads();

    unsigned short* src = Ma;
    unsigned short* dst = Mb;
    for (int it = 0; it < 8; ++it) {
      floatx4 f[4] = {};
      for (int s = 0; s < 2; ++s) {
        const int kb = 32 * s + 8 * q;
        uint4 ua4 = *(const uint4*)(src + (16 * wv + l15) * MP + kb);
        bf16x8 av = __builtin_bit_cast(bf16x8, ua4);
        for (int tn = 0; tn < 4; ++tn) {
          const int n = 16 * tn + l15;
          ushortx8 ub;
          #pragma unroll
          for (int j = 0; j < 8; ++j) ub[j] = src[(kb + j) * MP + n];
          bf16x8 bv = __builtin_bit_cast(bf16x8, ub);
          f[tn] = __builtin_amdgcn_mfma_f32_16x16x32_bf16(av, bv, f[tn], 0, 0, 0);
        }
      }
      float m2 = 0.f;
      for (int tn = 0; tn < 4; ++tn)
        for (int r = 0; r < 4; ++r) m2 = fmaxf(m2, fabsf(f[tn][r]));
      for (int off = 32; off; off >>= 1) m2 = fmaxf(m2, __shfl_xor(m2, off));
      if (lane == 0) red[wv] = m2;
      __syncthreads();
      {
        float gm2  = fmaxf(fmaxf(red[0], red[1]), fmaxf(red[2], red[3]));
        float inv2 = 1.f / gm2;
        for (int tn = 0; tn < 4; ++tn)
          for (int r = 0; r < 4; ++r)
            dst[(16 * wv + 4 * q + r) * MP + 16 * tn + l15] = f2bf(f[tn][r] * inv2);
      }
      __syncthreads();
      unsigned short* t2 = src; src = dst; dst = t2;
    }

    if (tid == 0) {
      int jb = 0; float best = -1.f;
      for (int j = 0; j < 64; ++j) {
        float dv = bf2f(src[j * MP + j]);
        if (dv > best) { best = dv; jb = j; }
      }
      *jsh = jb;
    }
    __syncthreads();
    if (tid < 64) vsh[tid] = bf2f(src[tid * MP + *jsh]);
    __syncthreads();

    if (wv == 0) {
      float wa = 0.f, wb = 0.f;
      for (int i = 0; i < 64; ++i) {
        float vi = vsh[i];
        wa = fmaf(W[i * 128 + lane], vi, wa);
        wb = fmaf(W[i * 128 + 64 + lane], vi, wb);
      }
      float num = wa * wa + wb * wb;
      float den = vsh[lane] * vsh[lane];
      for (int off = 32; off; off >>= 1) {
        num += __shfl_xor(num, off);
        den += __shfl_xor(den, off);
      }
      if (lane == 0) sig[0] = 1.f / sqrtf(num / den);
    }
    return;
  }

  // ---------------- GEMM path ----------------
  unsigned short* Wh = (unsigned short*)smem;   // [64][GP]
  unsigned short* Wl = Wh + 64 * GP;

  // stage W -> bf16 hi/lo in LDS (coalesced float4 loads)
  #pragma unroll
  for (int j = 0; j < 8; ++j) {
    const int v = tid + 256 * j;           // float4 index, 0..2047
    float4 w4 = ((const float4*)W)[v];
    const int e = v * 4;
    const int row = e >> 7, col = e & 127;
    float a[4] = {w4.x, w4.y, w4.z, w4.w};
    unsigned short h[4], l[4];
    #pragma unroll
    for (int i = 0; i < 4; ++i) {
      h[i] = f2bf(a[i]);
      l[i] = f2bf(a[i] - bf2f(h[i]));
    }
    unsigned hp0 = (unsigned)h[0] | ((unsigned)h[1] << 16);
    unsigned hp1 = (unsigned)h[2] | ((unsigned)h[3] << 16);
    unsigned lp0 = (unsigned)l[0] | ((unsigned)l[1] << 16);
    unsigned lp1 = (unsigned)l[2] | ((unsigned)l[3] << 16);
    *(uint2*)(Wh + row * GP + col) = make_uint2(hp0, hp1);
    *(uint2*)(Wl + row * GP + col) = make_uint2(lp0, lp1);
  }
  __syncthreads();

  const int R0 = blockIdx.x * 64 + wv * 16;   // 16 rows per wave
  floatx4 acc[4] = {};

  #pragma unroll
  for (int s = 0; s < 4; ++s) {
    const float* xp = x + ((size_t)(R0 + l15) << 7) + 32 * s + 8 * q;
    float4 x0 = *(const float4*)xp;
    float4 x1 = *(const float4*)(xp + 4);
    float xs8[8] = {x0.x, x0.y, x0.z, x0.w, x1.x, x1.y, x1.z, x1.w};
    ushortx8 uh, ul;
    #pragma unroll
    for (int j = 0; j < 8; ++j) {
      unsigned short h = f2bf(xs8[j]);
      uh[j] = h;
      ul[j] = f2bf(xs8[j] - bf2f(h));
    }
    bf16x8 ah = __builtin_bit_cast(bf16x8, uh);
    bf16x8 al = __builtin_bit_cast(bf16x8, ul);

    #pragma unroll
    for (int t = 0; t < 4; ++t) {
      const unsigned short* bp = Wh + (16 * t + l15) * GP + 32 * s + 8 * q;
      bf16x8 bh = __builtin_bit_cast(bf16x8, *(const uint4*)bp);
      const unsigned short* bq = Wl + (16 * t + l15) * GP + 32 * s + 8 * q;
      bf16x8 bl = __builtin_bit_cast(bf16x8, *(const uint4*)bq);
      acc[t] = __builtin_amdgcn_mfma_f32_16x16x32_bf16(ah, bh, acc[t], 0, 0, 0);
      acc[t] = __builtin_amdgcn_mfma_f32_16x16x32_bf16(al, bh, acc[t], 0, 0, 0);
      acc[t] = __builtin_amdgcn_mfma_f32_16x16x32_bf16(ah, bl, acc[t], 0, 0, 0);
    }
  }

  // store: C layout col = l15, row = 4q + r
  #pragma unroll
  for (int t = 0; t < 4; ++t)
    #pragma unroll
    for (int r = 0; r < 4; ++r)
      V[(size_t)(R0 + 4 * q + r) * 64 + 16 * t + l15] = acc[t][r];
}

// ---------------------------------------------------------------------------
// Fused scan: replaces phaseA + segagg + segscan + phaseC.
// Grid 256 blocks x 1024 threads. Block g: b = g>>5, time stripe tb = g&31
// (256 timesteps). Wave w (16 waves) owns one 16-step chunk, lane = k.
//
// R2 post-mortem: compiler scheduled phase-1 with ~1-iteration load/use
// distance (VGPR=60, VALUBusy 6.5%, 97 us) -> 16 serial memory-latency
// exposures. Fix: issue ALL 48 cache loads (one base reg + imm offsets)
// plus the 32 uniform tm/dt loads BEFORE any compute, pinned with
// sched_barrier(0); consume via compiler vmcnt(N). The raw (a,o,v) regs are
// overwritten in place with (ar,ai,u) so phase 3 still replays from regs.
// __launch_bounds__(1024,4): VGPR cap 128, 1 block/CU (deadlock-free spin).
// ---------------------------------------------------------------------------
__global__ __launch_bounds__(1024, 4) void k_fused(
    const float* __restrict__ am, const float* __restrict__ om,
    const float* __restrict__ tm, const float* __restrict__ dtp,
    const float* __restrict__ V,  const float* __restrict__ sr,
    const float* __restrict__ si, const float* __restrict__ traw,
    const float* __restrict__ bb, const float* __restrict__ sig,
    float* __restrict__ BA, int* __restrict__ FL,
    float* __restrict__ out) {
  __shared__ float4 sAgg[16 * 64];   // per-chunk transforms (A,U), 16 KB

  const int tid  = threadIdx.x;
  const int lane = tid & 63;
  const int w    = __builtin_amdgcn_readfirstlane(tid >> 6);  // chunk 0..15
  const int g    = blockIdx.x;       // 0..255
  const int b    = g >> 5;
  const int tb   = g & 31;
  const int gb   = g & ~31;

  const int bt0 = b * T_ + tb * 256 + w * TC;
  const float* pa = am  + (size_t)bt0 * 64 + lane;
  const float* po = om  + (size_t)bt0 * 64 + lane;
  const float* pv = V   + (size_t)bt0 * 64 + lane;

  // ---- Phase 1a: issue ALL loads up front (one exposure, not 16) ----
  float ca[TC], co[TC], cv[TC], ctm[TC], cdt[TC];
  #pragma unroll
  for (int t = 0; t < TC; ++t) {
    ca[t] = pa[64 * t];        // imm offsets 0..3840, single base reg
    co[t] = po[64 * t];
    cv[t] = pv[64 * t];
  }
  #pragma unroll
  for (int t = 0; t < TC; ++t) {
    ctm[t] = tm[bt0 + t];      // wave-uniform -> scalar loads
    cdt[t] = dtp[bt0 + t];
  }
  __builtin_amdgcn_sched_barrier(0);   // pin: all loads issued before compute

  const float tau    = log1pf(__expf(traw[0])) + 1e-3f;
  const float alpha0 = (log1pf(__expf(sr[lane])) + 1e-6f) * tau;
  const float omega0 = si[lane] * tau;
  const float bk     = bb[lane];
  const float invs   = sig[0];

  // ---- Phase 1b: per-step coefficients (overwrite cache in place) ----
  float Ar = 1.f, Ai = 0.f, Ur = 0.f, Ui = 0.f;
  #pragma unroll
  for (int t = 0; t < TC; ++t) {
    float tmv = ctm[t];
    float dtv = cdt[t];
    float alpha = alpha0 * __expf(ca[t] + tmv);
    float omega = omega0 * __expf(co[t] + tmv);
    float rho = __expf(-alpha * dtv);
    float th  = omega * dtv;
    float th2 = th * th;
    float st  = th * fmaf(th2, -0.16666667f, 1.f);  // |theta|<1.6e-3: exact
    float ct  = fmaf(th2, -0.5f, 1.f);
    float ar  = rho * ct, ai = rho * st;
    float u   = fmaf(cv[t], invs, bk);
    ca[t] = ar; co[t] = ai; cv[t] = u;              // reuse the same regs
    float nUr = fmaf(ar, Ur, fmaf(-ai, Ui, u));
    float nUi = fmaf(ar, Ui, ai * Ur);
    Ur = nUr; Ui = nUi;
    float nAr = fmaf(ar, Ar, -ai * Ai);
    float nAi = fmaf(ar, Ai, ai * Ar);
    Ar = nAr; Ai = nAi;
  }
  sAgg[w * 64 + lane] = make_float4(Ar, Ai, Ur, Ui);
  __syncthreads();

  // ---- exclusive within-block prefix E over chunks 0..w-1 ----
  // Always-load all 15 predecessors (independent LDS reads pipeline);
  // compose predicated with the identity so the chain stays branch-free.
  float Er = 1.f, Ei = 0.f, Fr = 0.f, Fi = 0.f;
  #pragma unroll
  for (int j = 0; j < 15; ++j) {
    float4 a = sAgg[j * 64 + lane];
    bool p = (j < w);
    float ax = p ? a.x : 1.f;
    float ay = p ? a.y : 0.f;
    float az = p ? a.z : 0.f;
    float aw_ = p ? a.w : 0.f;
    float nEr = ax * Er - ay * Ei;
    float nEi = ax * Ei + ay * Er;
    float nFr = fmaf(ax, Fr, fmaf(-ay, Fi, az));
    float nFi = fmaf(ax, Fi, fmaf(ay, Fr, aw_));
    Er = nEr; Ei = nEi; Fr = nFr; Fi = nFi;
  }

  // ---- wave 15 publishes the block aggregate = chunk15 ∘ E15 ----
  if (w == 15) {
    float bAr = Ar * Er - Ai * Ei;
    float bAi = Ar * Ei + Ai * Er;
    float bUr = fmaf(Ar, Fr, fmaf(-Ai, Fi, Ur));
    float bUi = fmaf(Ar, Fi, fmaf(Ai, Fr, Ui));
    *(float4*)(BA + (size_t)(g * 64 + lane) * 4) = make_float4(bAr, bAi, bUr, bUi);
    __threadfence();            // agent-scope writeback before flag release
  }
  __syncthreads();
  if (tid == 0)
    __hip_atomic_store(&FL[g], 1, __ATOMIC_RELEASE, __HIP_MEMORY_SCOPE_AGENT);

  // ---- Phase 2: wait for same-b predecessors, compose incoming state ----
  if (tid < tb) {
    while (__hip_atomic_load(&FL[gb + tid], __ATOMIC_ACQUIRE,
                             __HIP_MEMORY_SCOPE_AGENT) == 0)
      __builtin_amdgcn_s_sleep(2);
  }
  __syncthreads();
  __threadfence();              // acquire-side invalidate for all readers

  // Compose predecessors in batches of 8: loads within a batch are
  // independent (one latency exposure per batch, max 4) instead of 31
  // serial dependent loads. OOB lanes compose with the identity.
  float Hr = 0.f, Hi = 0.f;
  for (int j0 = 0; j0 < tb; j0 += 8) {
    float4 a[8];
    #pragma unroll
    for (int j = 0; j < 8; ++j) {
      if (j0 + j < tb)
        a[j] = *(const float4*)(BA + (size_t)((gb + j0 + j) * 64 + lane) * 4);
      else
        a[j] = make_float4(1.f, 0.f, 0.f, 0.f);
    }
    #pragma unroll
    for (int j = 0; j < 8; ++j) {
      float nHr = fmaf(a[j].x, Hr, fmaf(-a[j].y, Hi, a[j].z));
      float nHi = fmaf(a[j].x, Hi, fmaf(a[j].y, Hr, a[j].w));
      Hr = nHr; Hi = nHi;
    }
  }
  // state entering this wave's chunk: z0 = E.A * H + E.U
  float zr = fmaf(Er, Hr, fmaf(-Ei, Hi, Fr));
  float zi = fmaf(Er, Hi, fmaf(Ei, Hr, Fi));

  // ---- Phase 3: replay from register cache, write output ----
  float* outp = out + (size_t)bt0 * 128 + lane;
  #pragma unroll
  for (int t = 0; t < TC; ++t) {
    float nr = fmaf(ca[t], zr, fmaf(-co[t], zi, cv[t]));
    float ni = fmaf(ca[t], zi, co[t] * zr);
    zr = nr; zi = ni;
    outp[0]  = zr;     // C
    outp[64] = zi;     // S
    outp += 128;
  }
}

// ---------------------------------------------------------------------------
extern "C" void kernel_launch(void* const* d_in, const int* in_sizes, int n_in,
                              void* d_out, int out_size, void* d_ws, size_t ws_size,
                              hipStream_t stream) {
  (void)in_sizes; (void)n_in; (void)out_size; (void)ws_size;
  const float* x    = (const float*)d_in[0];
  const float* dtp  = (const float*)d_in[1];
  const float* amod = (const float*)d_in[2];
  const float* omod = (const float*)d_in[3];
  const float* tmod = (const float*)d_in[4];
  const float* srr  = (const float*)d_in[5];
  const float* sim  = (const float*)d_in[6];
  const float* traw = (const float*)d_in[7];
  const float* W    = (const float*)d_in[8];
  const float* bb   = (const float*)d_in[9];
  float* out = (float*)d_out;
  float* ws  = (float*)d_ws;

  float* sig = ws;                                   // [16]
  float* V   = ws + 16;                              // B*T*K = 4,194,304
  float* BA  = V + (size_t)B_ * T_ * K_;             // 256*64*4 = 65,536
  int*   FL  = (int*)(BA + 256 * 64 * 4);            // [256]

  k_gemm_sigma<<<GEMM_BLOCKS + 1, 256, 0, stream>>>(x, W, V, sig, FL);
  k_fused<<<256, 1024, 0, stream>>>(amod, omod, tmod, dtp, V, srr, sim, traw,
                                    bb, sig, BA, FL, out);
}

// Round 4
// 159.149 us; speedup vs baseline: 1.4631x; 1.3766x over previous
//
#include <hip/hip_runtime.h>
#include <hip/hip_bf16.h>

// Problem constants
#define B_   8
#define T_   8192
#define D_   128
#define K_   64
#define TC   16      // timesteps per chunk (one wave's serial run)

#define GEMM_BLOCKS 1024
#define GP 136       // LDS pitch (ushorts) for W hi/lo rows: 2-way bank aliasing only

typedef float  floatx4  __attribute__((ext_vector_type(4)));
typedef __bf16 bf16x8   __attribute__((ext_vector_type(8)));
typedef unsigned short ushortx8 __attribute__((ext_vector_type(8)));

__device__ inline unsigned short f2bf(float f) {
  unsigned u = __float_as_uint(f);
  u = u + 0x7FFFu + ((u >> 16) & 1u);   // RNE to bf16
  return (unsigned short)(u >> 16);
}
__device__ inline float bf2f(unsigned short h) {
  return __uint_as_float(((unsigned)h) << 16);
}

// ---------------------------------------------------------------------------
// K1+K2 fused: blocks 0..1023 do the GEMM V = x * W^T (unscaled, fp32-accurate
// via bf16 hi/lo split + MFMA); block 1024 computes 1/sigma into sig[0] and
// zeroes the cross-block flags used by the fused scan kernel.
// ---------------------------------------------------------------------------
#define MP 72  // sigma-path LDS pitch (ushorts)

__global__ __launch_bounds__(256) void k_gemm_sigma(
    const float* __restrict__ x, const float* __restrict__ W,
    float* __restrict__ V, float* __restrict__ sig, int* __restrict__ FL) {
  __shared__ __align__(16) unsigned char smem[2 * 64 * GP * 2 + 512];

  const int tid  = threadIdx.x;
  const int lane = tid & 63;
  const int wv   = tid >> 6;
  const int l15  = lane & 15;
  const int q    = lane >> 4;

  if (blockIdx.x == GEMM_BLOCKS) {
    // flags for k_fused (workspace is poisoned between replays; this kernel
    // strictly precedes k_fused on the stream, so zeroing here is safe)
    FL[tid] = 0;

    // ---------------- sigma path (one block) ----------------
    unsigned short* Ma = (unsigned short*)smem;            // 64*72
    unsigned short* Mb = Ma + 64 * MP;                     // 64*72
    float* red = (float*)(smem + 2 * 64 * MP * 2);
    float* vsh = red + 4;
    int*   jsh = (int*)(vsh + 64);

    // G = W W^T : tiles (tm=wv, tn=0..3), K=128 in 4 steps of 32
    floatx4 acc[4] = {};
    const int arow = 16 * wv + l15;
    for (int s = 0; s < 4; ++s) {
      const int kb = 32 * s + 8 * q;
      float4 a0 = *(const float4*)(W + arow * 128 + kb);
      float4 a1 = *(const float4*)(W + arow * 128 + kb + 4);
      ushortx8 ua;
      ua[0] = f2bf(a0.x); ua[1] = f2bf(a0.y); ua[2] = f2bf(a0.z); ua[3] = f2bf(a0.w);
      ua[4] = f2bf(a1.x); ua[5] = f2bf(a1.y); ua[6] = f2bf(a1.z); ua[7] = f2bf(a1.w);
      bf16x8 av = __builtin_bit_cast(bf16x8, ua);
      for (int tn = 0; tn < 4; ++tn) {
        const int brow = 16 * tn + l15;          // B[k][n] = W[n][k]
        float4 b0 = *(const float4*)(W + brow * 128 + kb);
        float4 b1 = *(const float4*)(W + brow * 128 + kb + 4);
        ushortx8 ub;
        ub[0] = f2bf(b0.x); ub[1] = f2bf(b0.y); ub[2] = f2bf(b0.z); ub[3] = f2bf(b0.w);
        ub[4] = f2bf(b1.x); ub[5] = f2bf(b1.y); ub[6] = f2bf(b1.z); ub[7] = f2bf(b1.w);
        bf16x8 bv = __builtin_bit_cast(bf16x8, ub);
        acc[tn] = __builtin_amdgcn_mfma_f32_16x16x32_bf16(av, bv, acc[tn], 0, 0, 0);
      }
    }
    float mx = 0.f;
    for (int tn = 0; tn < 4; ++tn)
      for (int r = 0; r < 4; ++r) mx = fmaxf(mx, fabsf(acc[tn][r]));
    for (int off = 32; off; off >>= 1) mx = fmaxf(mx, __shfl_xor(mx, off));
    if (lane == 0) red[wv] = mx;
    __syncthreads();
    {
      float gm  = fmaxf(fmaxf(red[0], red[1]), fmaxf(red[2], red[3]));
      float inv = 1.f / gm;
      for (int tn = 0; tn < 4; ++tn)
        for (int r = 0; r < 4; ++r)
          Ma[(16 * wv + 4 * q + r) * MP + 16 * tn + l15] = f2bf(acc[tn][r] * inv);
    }
    __syncthreads();

    unsigned short* src = Ma;
    unsigned short* dst = Mb;
    for (int it = 0; it < 8; ++it) {
      floatx4 f[4] = {};
      for (int s = 0; s < 2; ++s) {
        const int kb = 32 * s + 8 * q;
        uint4 ua4 = *(const uint4*)(src + (16 * wv + l15) * MP + kb);
        bf16x8 av = __builtin_bit_cast(bf16x8, ua4);
        for (int tn = 0; tn < 4; ++tn) {
          const int n = 16 * tn + l15;
          ushortx8 ub;
          #pragma unroll
          for (int j = 0; j < 8; ++j) ub[j] = src[(kb + j) * MP + n];
          bf16x8 bv = __builtin_bit_cast(bf16x8, ub);
          f[tn] = __builtin_amdgcn_mfma_f32_16x16x32_bf16(av, bv, f[tn], 0, 0, 0);
        }
      }
      float m2 = 0.f;
      for (int tn = 0; tn < 4; ++tn)
        for (int r = 0; r < 4; ++r) m2 = fmaxf(m2, fabsf(f[tn][r]));
      for (int off = 32; off; off >>= 1) m2 = fmaxf(m2, __shfl_xor(m2, off));
      if (lane == 0) red[wv] = m2;
      __syncthreads();
      {
        float gm2  = fmaxf(fmaxf(red[0], red[1]), fmaxf(red[2], red[3]));
        float inv2 = 1.f / gm2;
        for (int tn = 0; tn < 4; ++tn)
          for (int r = 0; r < 4; ++r)
            dst[(16 * wv + 4 * q + r) * MP + 16 * tn + l15] = f2bf(f[tn][r] * inv2);
      }
      __syncthreads();
      unsigned short* t2 = src; src = dst; dst = t2;
    }

    if (tid == 0) {
      int jb = 0; float best = -1.f;
      for (int j = 0; j < 64; ++j) {
        float dv = bf2f(src[j * MP + j]);
        if (dv > best) { best = dv; jb = j; }
      }
      *jsh = jb;
    }
    __syncthreads();
    if (tid < 64) vsh[tid] = bf2f(src[tid * MP + *jsh]);
    __syncthreads();

    if (wv == 0) {
      float wa = 0.f, wb = 0.f;
      for (int i = 0; i < 64; ++i) {
        float vi = vsh[i];
        wa = fmaf(W[i * 128 + lane], vi, wa);
        wb = fmaf(W[i * 128 + 64 + lane], vi, wb);
      }
      float num = wa * wa + wb * wb;
      float den = vsh[lane] * vsh[lane];
      for (int off = 32; off; off >>= 1) {
        num += __shfl_xor(num, off);
        den += __shfl_xor(den, off);
      }
      if (lane == 0) sig[0] = 1.f / sqrtf(num / den);
    }
    return;
  }

  // ---------------- GEMM path ----------------
  unsigned short* Wh = (unsigned short*)smem;   // [64][GP]
  unsigned short* Wl = Wh + 64 * GP;

  // stage W -> bf16 hi/lo in LDS (coalesced float4 loads)
  #pragma unroll
  for (int j = 0; j < 8; ++j) {
    const int v = tid + 256 * j;           // float4 index, 0..2047
    float4 w4 = ((const float4*)W)[v];
    const int e = v * 4;
    const int row = e >> 7, col = e & 127;
    float a[4] = {w4.x, w4.y, w4.z, w4.w};
    unsigned short h[4], l[4];
    #pragma unroll
    for (int i = 0; i < 4; ++i) {
      h[i] = f2bf(a[i]);
      l[i] = f2bf(a[i] - bf2f(h[i]));
    }
    unsigned hp0 = (unsigned)h[0] | ((unsigned)h[1] << 16);
    unsigned hp1 = (unsigned)h[2] | ((unsigned)h[3] << 16);
    unsigned lp0 = (unsigned)l[0] | ((unsigned)l[1] << 16);
    unsigned lp1 = (unsigned)l[2] | ((unsigned)l[3] << 16);
    *(uint2*)(Wh + row * GP + col) = make_uint2(hp0, hp1);
    *(uint2*)(Wl + row * GP + col) = make_uint2(lp0, lp1);
  }
  __syncthreads();

  const int R0 = blockIdx.x * 64 + wv * 16;   // 16 rows per wave
  floatx4 acc[4] = {};

  #pragma unroll
  for (int s = 0; s < 4; ++s) {
    const float* xp = x + ((size_t)(R0 + l15) << 7) + 32 * s + 8 * q;
    float4 x0 = *(const float4*)xp;
    float4 x1 = *(const float4*)(xp + 4);
    float xs8[8] = {x0.x, x0.y, x0.z, x0.w, x1.x, x1.y, x1.z, x1.w};
    ushortx8 uh, ul;
    #pragma unroll
    for (int j = 0; j < 8; ++j) {
      unsigned short h = f2bf(xs8[j]);
      uh[j] = h;
      ul[j] = f2bf(xs8[j] - bf2f(h));
    }
    bf16x8 ah = __builtin_bit_cast(bf16x8, uh);
    bf16x8 al = __builtin_bit_cast(bf16x8, ul);

    #pragma unroll
    for (int t = 0; t < 4; ++t) {
      const unsigned short* bp = Wh + (16 * t + l15) * GP + 32 * s + 8 * q;
      bf16x8 bh = __builtin_bit_cast(bf16x8, *(const uint4*)bp);
      const unsigned short* bq = Wl + (16 * t + l15) * GP + 32 * s + 8 * q;
      bf16x8 bl = __builtin_bit_cast(bf16x8, *(const uint4*)bq);
      acc[t] = __builtin_amdgcn_mfma_f32_16x16x32_bf16(ah, bh, acc[t], 0, 0, 0);
      acc[t] = __builtin_amdgcn_mfma_f32_16x16x32_bf16(al, bh, acc[t], 0, 0, 0);
      acc[t] = __builtin_amdgcn_mfma_f32_16x16x32_bf16(ah, bl, acc[t], 0, 0, 0);
    }
  }

  // store: C layout col = l15, row = 4q + r
  #pragma unroll
  for (int t = 0; t < 4; ++t)
    #pragma unroll
    for (int r = 0; r < 4; ++r)
      V[(size_t)(R0 + 4 * q + r) * 64 + 16 * t + l15] = acc[t][r];
}

// ---------------------------------------------------------------------------
// Fused scan. Grid 256 blocks x 1024 threads. Block g: b = g>>5, time stripe
// tb = g&31 (256 timesteps). Wave w (16 waves) owns one 16-step chunk,
// lane = k.
//
// R3 post-mortem: load scheduling changes (R2->R3) moved NOTHING; the ~85%
// stall is the device-scope sync storm: 16 acquire-threadfences per block
// (each = wbl2+inv, full vmcnt drain) + per-poll ACQUIRE invalidates =
// >4000 serialized TCC cache-maintenance ops device-wide. This round
// collapses sync to 2 fences/block:
//   - polls: RELAXED agent atomic loads (coherent, no invalidate), wave 0
//   - ONE acquire __threadfence by wave 0; wave 0 alone reads predecessor
//     aggregates, composes H, shares it via 512 B of LDS
//   - publish: syncthreads (drains BA stores to L2) + tid0 fence + release
// Other 15 waves issue no global reads in phase 2 -> no stale-L1 exposure.
// ---------------------------------------------------------------------------
__global__ __launch_bounds__(1024, 4) void k_fused(
    const float* __restrict__ am, const float* __restrict__ om,
    const float* __restrict__ tm, const float* __restrict__ dtp,
    const float* __restrict__ V,  const float* __restrict__ sr,
    const float* __restrict__ si, const float* __restrict__ traw,
    const float* __restrict__ bb, const float* __restrict__ sig,
    float* __restrict__ BA, int* __restrict__ FL,
    float* __restrict__ out) {
  __shared__ float4 sAgg[16 * 64];   // per-chunk transforms (A,U), 16 KB
  __shared__ float2 sH[64];          // incoming state per lane (k)

  const int tid  = threadIdx.x;
  const int lane = tid & 63;
  const int w    = __builtin_amdgcn_readfirstlane(tid >> 6);  // chunk 0..15
  const int g    = blockIdx.x;       // 0..255
  const int b    = g >> 5;
  const int tb   = g & 31;
  const int gb   = g & ~31;

  const int bt0 = b * T_ + tb * 256 + w * TC;
  const float* pa = am  + (size_t)bt0 * 64 + lane;
  const float* po = om  + (size_t)bt0 * 64 + lane;
  const float* pv = V   + (size_t)bt0 * 64 + lane;

  // ---- Phase 1a: issue ALL loads up front ----
  float ca[TC], co[TC], cv[TC], ctm[TC], cdt[TC];
  #pragma unroll
  for (int t = 0; t < TC; ++t) {
    ca[t] = pa[64 * t];        // imm offsets, single base reg
    co[t] = po[64 * t];
    cv[t] = pv[64 * t];
  }
  #pragma unroll
  for (int t = 0; t < TC; ++t) {
    ctm[t] = tm[bt0 + t];      // wave-uniform -> scalar loads
    cdt[t] = dtp[bt0 + t];
  }
  __builtin_amdgcn_sched_barrier(0);

  const float tau    = log1pf(__expf(traw[0])) + 1e-3f;
  const float alpha0 = (log1pf(__expf(sr[lane])) + 1e-6f) * tau;
  const float omega0 = si[lane] * tau;
  const float bk     = bb[lane];
  const float invs   = sig[0];

  // ---- Phase 1b: per-step coefficients (overwrite cache in place) ----
  float Ar = 1.f, Ai = 0.f, Ur = 0.f, Ui = 0.f;
  #pragma unroll
  for (int t = 0; t < TC; ++t) {
    float tmv = ctm[t];
    float dtv = cdt[t];
    float alpha = alpha0 * __expf(ca[t] + tmv);
    float omega = omega0 * __expf(co[t] + tmv);
    float rho = __expf(-alpha * dtv);
    float th  = omega * dtv;
    float th2 = th * th;
    float st  = th * fmaf(th2, -0.16666667f, 1.f);  // |theta|<1.6e-3: exact
    float ct  = fmaf(th2, -0.5f, 1.f);
    float ar  = rho * ct, ai = rho * st;
    float u   = fmaf(cv[t], invs, bk);
    ca[t] = ar; co[t] = ai; cv[t] = u;              // reuse the same regs
    float nUr = fmaf(ar, Ur, fmaf(-ai, Ui, u));
    float nUi = fmaf(ar, Ui, ai * Ur);
    Ur = nUr; Ui = nUi;
    float nAr = fmaf(ar, Ar, -ai * Ai);
    float nAi = fmaf(ar, Ai, ai * Ar);
    Ar = nAr; Ai = nAi;
  }
  sAgg[w * 64 + lane] = make_float4(Ar, Ai, Ur, Ui);
  __syncthreads();

  // ---- exclusive within-block prefix E over chunks 0..w-1 ----
  float Er = 1.f, Ei = 0.f, Fr = 0.f, Fi = 0.f;
  #pragma unroll
  for (int j = 0; j < 15; ++j) {
    float4 a = sAgg[j * 64 + lane];
    bool p = (j < w);
    float ax = p ? a.x : 1.f;
    float ay = p ? a.y : 0.f;
    float az = p ? a.z : 0.f;
    float aw_ = p ? a.w : 0.f;
    float nEr = ax * Er - ay * Ei;
    float nEi = ax * Ei + ay * Er;
    float nFr = fmaf(ax, Fr, fmaf(-ay, Fi, az));
    float nFi = fmaf(ax, Fi, fmaf(ay, Fr, aw_));
    Er = nEr; Ei = nEi; Fr = nFr; Fi = nFi;
  }

  // ---- wave 15 publishes the block aggregate = chunk15 ∘ E15 ----
  if (w == 15) {
    float bAr = Ar * Er - Ai * Ei;
    float bAi = Ar * Ei + Ai * Er;
    float bUr = fmaf(Ar, Fr, fmaf(-Ai, Fi, Ur));
    float bUi = fmaf(Ar, Fi, fmaf(Ai, Fr, Ui));
    *(float4*)(BA + (size_t)(g * 64 + lane) * 4) = make_float4(bAr, bAi, bUr, bUi);
  }
  __syncthreads();               // all waves' BA stores drained to L2 here
  if (tid == 0) {
    __threadfence();             // single release writeback for the block
    __hip_atomic_store(&FL[g], 1, __ATOMIC_RELEASE, __HIP_MEMORY_SCOPE_AGENT);
  }

  // ---- Phase 2: wave 0 only: poll (relaxed), one fence, compose H ----
  if (w == 0) {
    if (lane < tb) {
      while (__hip_atomic_load(&FL[gb + lane], __ATOMIC_RELAXED,
                               __HIP_MEMORY_SCOPE_AGENT) == 0)
        __builtin_amdgcn_s_sleep(2);
    }
    __threadfence();             // single acquire; orders BA loads below
    float Hr = 0.f, Hi = 0.f;
    for (int j0 = 0; j0 < tb; j0 += 8) {
      float4 a[8];
      #pragma unroll
      for (int j = 0; j < 8; ++j) {
        if (j0 + j < tb)
          a[j] = *(const float4*)(BA + (size_t)((gb + j0 + j) * 64 + lane) * 4);
        else
          a[j] = make_float4(1.f, 0.f, 0.f, 0.f);
      }
      #pragma unroll
      for (int j = 0; j < 8; ++j) {
        float nHr = fmaf(a[j].x, Hr, fmaf(-a[j].y, Hi, a[j].z));
        float nHi = fmaf(a[j].x, Hi, fmaf(a[j].y, Hr, a[j].w));
        Hr = nHr; Hi = nHi;
      }
    }
    sH[lane] = make_float2(Hr, Hi);
  }
  __syncthreads();

  float2 h = sH[lane];
  // state entering this wave's chunk: z0 = E ∘ H
  float zr = fmaf(Er, h.x, fmaf(-Ei, h.y, Fr));
  float zi = fmaf(Er, h.y, fmaf(Ei, h.x, Fi));

  // ---- Phase 3: replay from register cache, write output ----
  float* outp = out + (size_t)bt0 * 128 + lane;
  #pragma unroll
  for (int t = 0; t < TC; ++t) {
    float nr = fmaf(ca[t], zr, fmaf(-co[t], zi, cv[t]));
    float ni = fmaf(ca[t], zi, co[t] * zr);
    zr = nr; zi = ni;
    outp[0]  = zr;     // C
    outp[64] = zi;     // S
    outp += 128;
  }
}

// ---------------------------------------------------------------------------
extern "C" void kernel_launch(void* const* d_in, const int* in_sizes, int n_in,
                              void* d_out, int out_size, void* d_ws, size_t ws_size,
                              hipStream_t stream) {
  (void)in_sizes; (void)n_in; (void)out_size; (void)ws_size;
  const float* x    = (const float*)d_in[0];
  const float* dtp  = (const float*)d_in[1];
  const float* amod = (const float*)d_in[2];
  const float* omod = (const float*)d_in[3];
  const float* tmod = (const float*)d_in[4];
  const float* srr  = (const float*)d_in[5];
  const float* sim  = (const float*)d_in[6];
  const float* traw = (const float*)d_in[7];
  const float* W    = (const float*)d_in[8];
  const float* bb   = (const float*)d_in[9];
  float* out = (float*)d_out;
  float* ws  = (float*)d_ws;

  float* sig = ws;                                   // [16]
  float* V   = ws + 16;                              // B*T*K = 4,194,304
  float* BA  = V + (size_t)B_ * T_ * K_;             // 256*64*4 = 65,536
  int*   FL  = (int*)(BA + 256 * 64 * 4);            // [256]

  k_gemm_sigma<<<GEMM_BLOCKS + 1, 256, 0, stream>>>(x, W, V, sig, FL);
  k_fused<<<256, 1024, 0, stream>>>(amod, omod, tmod, dtp, V, srr, sim, traw,
                                    bb, sig, BA, FL, out);
}